// Round 1
// baseline (73.785 us; speedup 1.0000x reference)
//
#include <hip/hip_runtime.h>

// GaussianAdapter, fused single kernel.
// out[b,r,f] = sum_t(w*v) / sum_t(w),  w = exp(-alpha*(r-ts)^2)*(ts>0) + EPS
// B=16, T=512, R=128, F=32.
//
// Block = 1024 threads (16 waves = 4 waves/SIMD), grid = 256 = #CUs.
// Each block: one (b, 8-r tile). Full T staged once in 128 KB LDS.
//   f  = tid & 31          (feature)
//   rl = (tid>>5) & 3      (r-slot; each slot handles r=rl and r=rl+4 -> RPT=2)
//   tg = tid >> 7          (8 t-groups x 64 timesteps)
// Hot loop: 1 ds_read_b128 feeds 4 exp-paths (2 t x 2 r) -> ~6 VALU + 1 v_exp
// per element-r. log2e folded into alpha so exp2f() emits a bare v_exp_f32.
// No workspace use (d_ws untouched).

constexpr int B_ = 16, T_ = 512, R_ = 128, F_ = 32;
constexpr int NTG = 8;            // t-groups per block
constexpr int CT_ = T_ / NTG;     // 64 timesteps per t-group
constexpr int RSL = 4;            // r-slots
constexpr int RB_ = RSL * 2;      // 8 r per block (RPT=2)
constexpr float EPS_ = 1e-7f;
constexpr float LOG2E_ = 1.4426950408889634f;

__global__ __launch_bounds__(1024) void ga_fused(
    const float* __restrict__ ts_g, const float* __restrict__ v_g,
    const float* __restrict__ ref_g, const float* __restrict__ alpha_g,
    float* __restrict__ out)
{
    // Pair layout for b128 reads: float4 index q = (t>>1)*F + f holds
    // {ts(2k,f), v(2k,f), ts(2k+1,f), v(2k+1,f)}. 8192 float4 = 128 KB.
    __shared__ float4 tile[(T_ / 2) * F_];

    const int tid = threadIdx.x;
    const int rb  = blockIdx.x & (R_ / RB_ - 1);   // 16 r-blocks per b
    const int b   = blockIdx.x >> 4;
    const int f   = tid & 31;
    const int rl  = (tid >> 5) & (RSL - 1);
    const int tg  = tid >> 7;

    const float nega2 = -alpha_g[0] * LOG2E_;      // exp(x) == exp2(x*log2e)
    const float r0 = ref_g[b * R_ + rb * RB_ + rl];
    const float r1 = ref_g[b * R_ + rb * RB_ + rl + RSL];

    // ---- stage global -> LDS, folding the (ts>0) mask into a sentinel ----
    // sentinel 2e19: (nega2*d)*d overflows to -inf, exp2(-inf) = 0 exactly.
    const float4* tsg4 = (const float4*)(ts_g + (size_t)b * T_ * F_);
    const float4* vg4  = (const float4*)(v_g  + (size_t)b * T_ * F_);
    float2* dd = (float2*)tile;
    #pragma unroll
    for (int it = 0; it < (T_ * F_ / 4) / 1024; ++it) {
        const int i = tid + it * 1024;    // quad index: t = i>>3, fq = i&7
        float4 a = tsg4[i];
        float4 w = vg4[i];
        a.x = (a.x > 0.f) ? a.x : 2e19f;
        a.y = (a.y > 0.f) ? a.y : 2e19f;
        a.z = (a.z > 0.f) ? a.z : 2e19f;
        a.w = (a.w > 0.f) ? a.w : 2e19f;
        const int t   = i >> 3;
        const int fq  = i & 7;
        const int k   = t >> 1;
        const int par = t & 1;
        const int base = (k * F_ + fq * 4) * 2 + par;
        dd[base + 0] = make_float2(a.x, w.x);
        dd[base + 2] = make_float2(a.y, w.y);
        dd[base + 4] = make_float2(a.z, w.z);
        dd[base + 6] = make_float2(a.w, w.w);
    }
    __syncthreads();

    // ---- hot loop: 1 ds_read_b128 + 4 exp paths per iteration ----
    float num0 = 0.f, den0 = 0.f, num1 = 0.f, den1 = 0.f;
    const float4* src = tile + tg * (CT_ / 2) * F_ + f;
    #pragma unroll 8
    for (int k = 0; k < CT_ / 2; ++k) {
        const float4 tv = src[k * F_];
        const float d00 = r0 - tv.x, d10 = r1 - tv.x;
        const float d01 = r0 - tv.z, d11 = r1 - tv.z;
        const float e00 = exp2f((nega2 * d00) * d00);
        const float e10 = exp2f((nega2 * d10) * d10);
        const float e01 = exp2f((nega2 * d01) * d01);
        const float e11 = exp2f((nega2 * d11) * d11);
        const float w00 = e00 + EPS_, w10 = e10 + EPS_;
        const float w01 = e01 + EPS_, w11 = e11 + EPS_;
        den0 += w00 + w01;
        den1 += w10 + w11;
        num0 = fmaf(w00, tv.y, fmaf(w01, tv.w, num0));
        num1 = fmaf(w10, tv.y, fmaf(w11, tv.w, num1));
    }
    __syncthreads();

    // ---- in-block reduction across the 8 t-groups (reuse tile LDS) ----
    // red[rr 0..7][tg 0..7][f 0..31] float2
    float2* red = (float2*)tile;
    red[((rl      ) * NTG + tg) * F_ + f] = make_float2(num0, den0);
    red[((rl + RSL) * NTG + tg) * F_ + f] = make_float2(num1, den1);
    __syncthreads();

    if (tid < RB_ * F_) {
        const int rr = tid >> 5;            // f = tid & 31 (same lane mapping)
        float num = 0.f, den = 0.f;
        #pragma unroll
        for (int g = 0; g < NTG; ++g) {
            const float2 p = red[(rr * NTG + g) * F_ + f];
            num += p.x;
            den += p.y;
        }
        out[(size_t)(b * R_ + rb * RB_ + rr) * F_ + f] = num / den;
    }
}

extern "C" void kernel_launch(void* const* d_in, const int* in_sizes, int n_in,
                              void* d_out, int out_size, void* d_ws, size_t ws_size,
                              hipStream_t stream) {
    const float* timesteps = (const float*)d_in[0];   // (B,T,F)
    const float* values    = (const float*)d_in[1];   // (B,T,F)
    const float* ref_ts    = (const float*)d_in[2];   // (B,R)
    const float* alpha     = (const float*)d_in[3];   // (1,)
    float* out = (float*)d_out;                       // (B,R,F)
    // d_ws deliberately unused: single fused kernel, no partials.

    ga_fused<<<B_ * (R_ / RB_), 1024, 0, stream>>>(
        timesteps, values, ref_ts, alpha, out);
}

// Round 2
// 69.748 us; speedup vs baseline: 1.0579x; 1.0579x over previous
//
#include <hip/hip_runtime.h>

// GaussianAdapter, fused single kernel, v2.
// out[b,r,f] = sum_t(w*v) / sum_t(w),  w = exp(-alpha*(r-ts)^2)*(ts>0) + EPS
// B=16, T=512, R=128, F=32.
//
// Block = 1024 threads (16 waves = 4 waves/SIMD), grid = 256 = #CUs.
// Each block: one (b, 8-r tile). Full T staged once in 128 KB LDS.
//   f  = tid & 31          (feature)
//   rl = (tid>>5) & 3      (r-slot; each slot handles r=rl and r=rl+4 -> RPT=2)
//   tg = tid >> 7          (8 t-groups x 64 timesteps)
//
// v2 changes vs v1:
//  - __builtin_amdgcn_exp2f: bare v_exp_f32, no OCML denormal-fixup sequence
//    (sentinel still exact: nega2*d*d overflows to -inf, v_exp(-inf) = 0;
//    denormal-flush at the small end is invisible under EPS = 1e-7).
//  - EPS folded out of the hot loop: sum(e+EPS)*v = sum(e*v) + EPS*sum(v),
//    sum(e+EPS) = sum(e) + T*EPS. One shared sumv accumulator (2 ops/iter)
//    replaces 4 per-eval adds; correction applied once in the epilogue.
// Hot loop issue cost: 22 VALU*2cyc + 4 exp*8cyc = 76 cyc per 4 evals.

constexpr int B_ = 16, T_ = 512, R_ = 128, F_ = 32;
constexpr int NTG = 8;            // t-groups per block
constexpr int CT_ = T_ / NTG;     // 64 timesteps per t-group
constexpr int RSL = 4;            // r-slots
constexpr int RB_ = RSL * 2;      // 8 r per block (RPT=2)
constexpr float EPS_ = 1e-7f;
constexpr float LOG2E_ = 1.4426950408889634f;

__global__ __launch_bounds__(1024) void ga_fused(
    const float* __restrict__ ts_g, const float* __restrict__ v_g,
    const float* __restrict__ ref_g, const float* __restrict__ alpha_g,
    float* __restrict__ out)
{
    // Pair layout for b128 reads: float4 index q = (t>>1)*F + f holds
    // {ts(2k,f), v(2k,f), ts(2k+1,f), v(2k+1,f)}. 8192 float4 = 128 KB.
    __shared__ float4 tile[(T_ / 2) * F_];

    const int tid = threadIdx.x;
    const int rb  = blockIdx.x & (R_ / RB_ - 1);   // 16 r-blocks per b
    const int b   = blockIdx.x >> 4;
    const int f   = tid & 31;
    const int rl  = (tid >> 5) & (RSL - 1);
    const int tg  = tid >> 7;

    const float nega2 = -alpha_g[0] * LOG2E_;      // exp(x) == exp2(x*log2e)
    const float r0 = ref_g[b * R_ + rb * RB_ + rl];
    const float r1 = ref_g[b * R_ + rb * RB_ + rl + RSL];

    // ---- stage global -> LDS, folding the (ts>0) mask into a sentinel ----
    // sentinel 2e19: (nega2*d)*d overflows to -inf, v_exp(-inf) = 0 exactly.
    const float4* tsg4 = (const float4*)(ts_g + (size_t)b * T_ * F_);
    const float4* vg4  = (const float4*)(v_g  + (size_t)b * T_ * F_);
    float2* dd = (float2*)tile;
    #pragma unroll
    for (int it = 0; it < (T_ * F_ / 4) / 1024; ++it) {
        const int i = tid + it * 1024;    // quad index: t = i>>3, fq = i&7
        float4 a = tsg4[i];
        float4 w = vg4[i];
        a.x = (a.x > 0.f) ? a.x : 2e19f;
        a.y = (a.y > 0.f) ? a.y : 2e19f;
        a.z = (a.z > 0.f) ? a.z : 2e19f;
        a.w = (a.w > 0.f) ? a.w : 2e19f;
        const int t   = i >> 3;
        const int fq  = i & 7;
        const int k   = t >> 1;
        const int par = t & 1;
        const int base = (k * F_ + fq * 4) * 2 + par;
        dd[base + 0] = make_float2(a.x, w.x);
        dd[base + 2] = make_float2(a.y, w.y);
        dd[base + 4] = make_float2(a.z, w.z);
        dd[base + 6] = make_float2(a.w, w.w);
    }
    __syncthreads();

    // ---- hot loop: 1 ds_read_b128 + 4 raw-exp paths per iteration ----
    float num0 = 0.f, den0 = 0.f, num1 = 0.f, den1 = 0.f, sumv = 0.f;
    const float4* src = tile + tg * (CT_ / 2) * F_ + f;
    #pragma unroll 8
    for (int k = 0; k < CT_ / 2; ++k) {
        const float4 tv = src[k * F_];
        const float d00 = r0 - tv.x, d10 = r1 - tv.x;
        const float d01 = r0 - tv.z, d11 = r1 - tv.z;
        const float e00 = __builtin_amdgcn_exp2f((nega2 * d00) * d00);
        const float e10 = __builtin_amdgcn_exp2f((nega2 * d10) * d10);
        const float e01 = __builtin_amdgcn_exp2f((nega2 * d01) * d01);
        const float e11 = __builtin_amdgcn_exp2f((nega2 * d11) * d11);
        den0 += e00 + e01;
        den1 += e10 + e11;
        sumv += tv.y + tv.w;                 // shared across r0/r1
        num0 = fmaf(e00, tv.y, fmaf(e01, tv.w, num0));
        num1 = fmaf(e10, tv.y, fmaf(e11, tv.w, num1));
    }
    // EPS correction: this thread covered CT_ timesteps of the T-sum.
    num0 = fmaf(EPS_, sumv, num0);
    num1 = fmaf(EPS_, sumv, num1);
    den0 += (float)CT_ * EPS_;
    den1 += (float)CT_ * EPS_;
    __syncthreads();

    // ---- in-block reduction across the 8 t-groups (reuse tile LDS) ----
    // red[rr 0..7][tg 0..7][f 0..31] float2
    float2* red = (float2*)tile;
    red[((rl      ) * NTG + tg) * F_ + f] = make_float2(num0, den0);
    red[((rl + RSL) * NTG + tg) * F_ + f] = make_float2(num1, den1);
    __syncthreads();

    if (tid < RB_ * F_) {
        const int rr = tid >> 5;            // f = tid & 31 (same lane mapping)
        float num = 0.f, den = 0.f;
        #pragma unroll
        for (int g = 0; g < NTG; ++g) {
            const float2 p = red[(rr * NTG + g) * F_ + f];
            num += p.x;
            den += p.y;
        }
        out[(size_t)(b * R_ + rb * RB_ + rr) * F_ + f] = num / den;
    }
}

extern "C" void kernel_launch(void* const* d_in, const int* in_sizes, int n_in,
                              void* d_out, int out_size, void* d_ws, size_t ws_size,
                              hipStream_t stream) {
    const float* timesteps = (const float*)d_in[0];   // (B,T,F)
    const float* values    = (const float*)d_in[1];   // (B,T,F)
    const float* ref_ts    = (const float*)d_in[2];   // (B,R)
    const float* alpha     = (const float*)d_in[3];   // (1,)
    float* out = (float*)d_out;                       // (B,R,F)
    // d_ws deliberately unused: single fused kernel, no partials.

    ga_fused<<<B_ * (R_ / RB_), 1024, 0, stream>>>(
        timesteps, values, ref_ts, alpha, out);
}